// Round 9
// baseline (5027.284 us; speedup 1.0000x reference)
//
#include <hip/hip_runtime.h>
#include <math.h>

#define CDIM 256
#define NHEAD 8
#define HD 32
#define BSZ 8
#define NTOK 256
#define MROWS (BSZ*NTOK)   // 2048
#define LN_EPS 1e-5f
#define DT_STEP 0.01f

// Dynamic LDS layout for ode_kernel (bytes):
//   [0,      131072) : W1 as bf16, [col][k] layout, XOR-swizzled
//   [131072, 139264) : bufA[8][256] f32   (feval arg)
//   [139264, 147456) : bufB[8][256] f32   (relu(h))
//   [147456, 147968) : pS[8][16] f32      (LN sum partials, [row][wave])
//   [147968, 148480) : pQ[8][16] f32      (LN sumsq partials)
#define ODE_LDS_BYTES 148480

// ---------------------------------------------------------------------------
// LayerNorm statistics across 256 threads (one column each) for R rows.
// (used by oproj kernel only)
// ---------------------------------------------------------------------------
template<int R>
__device__ __forceinline__ void ln_stats(const float* val, int tid,
        float (*part_s)[R], float (*part_q)[R], float* mb, float* rb) {
    const int lane = tid & 63;
    const int wid  = tid >> 6;
    #pragma unroll
    for (int r = 0; r < R; ++r) {
        float s = val[r];
        float q = val[r] * val[r];
        #pragma unroll
        for (int off = 32; off > 0; off >>= 1) {
            s += __shfl_down(s, off, 64);
            q += __shfl_down(q, off, 64);
        }
        if (lane == 0) { part_s[wid][r] = s; part_q[wid][r] = q; }
    }
    __syncthreads();
    if (tid < R) {
        float S = part_s[0][tid] + part_s[1][tid] + part_s[2][tid] + part_s[3][tid];
        float Q = part_q[0][tid] + part_q[1][tid] + part_q[2][tid] + part_q[3][tid];
        float mean = S * (1.0f / CDIM);
        float var  = Q * (1.0f / CDIM) - mean * mean;
        mb[tid] = mean;
        rb[tid] = rsqrtf(var + LN_EPS);
    }
    __syncthreads();
}

// ---------------------------------------------------------------------------
// QKV projection: OUT[M][768] = X[M][256] @ W[256][768] + bias
// ---------------------------------------------------------------------------
__global__ __launch_bounds__(256) void qkv_kernel(
        const float* __restrict__ X, const float* __restrict__ W,
        const float* __restrict__ bias, float* __restrict__ OUT) {
    const int R = 8;
    __shared__ float xs[R][CDIM];
    const int base = blockIdx.x * R;
    const int tid = threadIdx.x;
    #pragma unroll
    for (int r = 0; r < R; ++r) xs[r][tid] = X[(size_t)(base + r) * CDIM + tid];
    __syncthreads();
    for (int g = 0; g < 3; ++g) {
        const int j = g * 256 + tid;
        float acc[R];
        #pragma unroll
        for (int r = 0; r < R; ++r) acc[r] = 0.0f;
        const float* wp = W + j;
        for (int k = 0; k < CDIM; k += 4) {
            float w0 = wp[(size_t)(k+0)*768];
            float w1 = wp[(size_t)(k+1)*768];
            float w2 = wp[(size_t)(k+2)*768];
            float w3 = wp[(size_t)(k+3)*768];
            #pragma unroll
            for (int r = 0; r < R; ++r) {
                float4 xv = *reinterpret_cast<const float4*>(&xs[r][k]);
                acc[r] = fmaf(xv.x, w0, acc[r]);
                acc[r] = fmaf(xv.y, w1, acc[r]);
                acc[r] = fmaf(xv.z, w2, acc[r]);
                acc[r] = fmaf(xv.w, w3, acc[r]);
            }
        }
        const float bb = bias[j];
        #pragma unroll
        for (int r = 0; r < R; ++r) OUT[(size_t)(base + r) * 768 + j] = acc[r] + bb;
    }
}

// ---------------------------------------------------------------------------
// Per-(b,h) attention with online softmax. One WG per (b,h); thread = query row.
// ---------------------------------------------------------------------------
__global__ __launch_bounds__(256) void attn_kernel(
        const float* __restrict__ QKV, float* __restrict__ PO) {
    __shared__ float ks[NTOK][HD];
    __shared__ float vs[NTOK][HD];
    const int bh = blockIdx.x;
    const int b = bh >> 3;
    const int h = bh & 7;
    const int tid = threadIdx.x;
    for (int idx = tid; idx < NTOK * HD; idx += 256) {
        const int j = idx >> 5;
        const int d = idx & 31;
        const float* row = QKV + (size_t)(b * NTOK + j) * 768 + h * HD + d;
        ks[j][d] = row[256];
        vs[j][d] = row[512];
    }
    __syncthreads();
    float q[HD];
    const float* qrow = QKV + (size_t)(b * NTOK + tid) * 768 + h * HD;
    #pragma unroll
    for (int d = 0; d < HD; ++d) q[d] = qrow[d];
    const float scale = 0.17677669529663687f;   // 1/sqrt(32)
    float m = -1e30f, l = 0.0f;
    float po[HD];
    #pragma unroll
    for (int d = 0; d < HD; ++d) po[d] = 0.0f;
    for (int j = 0; j < NTOK; ++j) {
        float s = 0.0f;
        #pragma unroll
        for (int d = 0; d < HD; ++d) s = fmaf(q[d], ks[j][d], s);
        s *= scale;
        const float nm = fmaxf(m, s);
        const float corr = __expf(m - nm);
        const float p = __expf(s - nm);
        l = l * corr + p;
        #pragma unroll
        for (int d = 0; d < HD; ++d) po[d] = fmaf(po[d], corr, p * vs[j][d]);
        m = nm;
    }
    const float inv = 1.0f / l;
    float* dst = PO + (size_t)(b * NTOK + tid) * CDIM + h * HD;
    #pragma unroll
    for (int d = 0; d < HD; ++d) dst[d] = po[d] * inv;
}

// ---------------------------------------------------------------------------
// Out-proj + bias + residual(x) + LayerNorm(g1,b1) -> X1
// ---------------------------------------------------------------------------
__global__ __launch_bounds__(256) void oproj_ln_kernel(
        const float* __restrict__ PO, const float* __restrict__ WO,
        const float* __restrict__ BO, const float* __restrict__ X,
        const float* __restrict__ G1, const float* __restrict__ B1,
        float* __restrict__ X1) {
    const int R = 8;
    __shared__ float ps[R][CDIM];
    __shared__ float part_s[4][R], part_q[4][R];
    __shared__ float mb[R], rb[R];
    const int base = blockIdx.x * R;
    const int tid = threadIdx.x;
    #pragma unroll
    for (int r = 0; r < R; ++r) ps[r][tid] = PO[(size_t)(base + r) * CDIM + tid];
    __syncthreads();
    float acc[R];
    #pragma unroll
    for (int r = 0; r < R; ++r) acc[r] = 0.0f;
    const float* wp = WO + tid;
    for (int k = 0; k < CDIM; k += 4) {
        float w0 = wp[(size_t)(k+0)*CDIM];
        float w1 = wp[(size_t)(k+1)*CDIM];
        float w2 = wp[(size_t)(k+2)*CDIM];
        float w3 = wp[(size_t)(k+3)*CDIM];
        #pragma unroll
        for (int r = 0; r < R; ++r) {
            float4 xv = *reinterpret_cast<const float4*>(&ps[r][k]);
            acc[r] = fmaf(xv.x, w0, acc[r]);
            acc[r] = fmaf(xv.y, w1, acc[r]);
            acc[r] = fmaf(xv.z, w2, acc[r]);
            acc[r] = fmaf(xv.w, w3, acc[r]);
        }
    }
    const float bo = BO[tid];
    float val[R];
    #pragma unroll
    for (int r = 0; r < R; ++r)
        val[r] = acc[r] + bo + X[(size_t)(base + r) * CDIM + tid];
    ln_stats<R>(val, tid, part_s, part_q, mb, rb);
    const float g = G1[tid], bb = B1[tid];
    #pragma unroll
    for (int r = 0; r < R; ++r)
        X1[(size_t)(base + r) * CDIM + tid] = (val[r] - mb[r]) * rb[r] * g + bb;
}

// ---------------------------------------------------------------------------
// Persistent ODE kernel, 64-VGPR edition.
//
// Rounds 3-8 proved the compiler pins this 1024-thread kernel at 64 VGPRs
// (occupancy heuristic; waves_per_eu/launch_bounds/dynamic-LDS cannot raise
// it), so the design now FITS 64 VGPRs:
//   thread t: col = t>>2 (0..255), kq = t&3. Lanes 4c..4c+3 of a wave share
//   a column -> kq-partials reduce via __shfl_xor (no LDS 'red' buffer).
//   W1: bf16 in LDS (128 KB), [col][k], byte-offset XOR-swizzle ^((col&7)<<4)
//       -> ds_read_b128 of a 16-col wave is <=2-way instead of 16-way.
//   W2: bf16 in registers, 8 named uint4 (32 VGPRs).
//   k-slices interleaved: thread kq handles k = c*32 + kq*8 + j, so the 4 kq
//   act-read addresses hit distinct bank groups (0/8/16/24) -> conflict-free.
//   3 barriers/feval.
// ---------------------------------------------------------------------------
struct WRegs { uint4 m0, m1, m2, m3, m4, m5, m6, m7; };

__device__ __forceinline__ unsigned int bf16_rne(float x) {
    unsigned int u = __float_as_uint(x);
    return (u + 0x7FFFu + ((u >> 16) & 1u)) >> 16;
}

// pack 8 k-weights (k = kstart..kstart+7, stride CDIM) of one column
__device__ __forceinline__ uint4 pack_w(const float* pcol, int kstart) {
    const float* p = pcol + (size_t)kstart * CDIM;
    unsigned int u0 = bf16_rne(p[0*CDIM]) | (bf16_rne(p[1*CDIM]) << 16);
    unsigned int u1 = bf16_rne(p[2*CDIM]) | (bf16_rne(p[3*CDIM]) << 16);
    unsigned int u2 = bf16_rne(p[4*CDIM]) | (bf16_rne(p[5*CDIM]) << 16);
    unsigned int u3 = bf16_rne(p[6*CDIM]) | (bf16_rne(p[7*CDIM]) << 16);
    return make_uint4(u0, u1, u2, u3);
}

// acc[0..7] += buf[r][kbase..kbase+7] * w[0..7]  (8 bf16 weights in pv)
__device__ __forceinline__ void fma_chunk(
        const float (*buf)[CDIM], int kbase, uint4 pv, float* acc) {
    const float w0 = __uint_as_float(pv.x << 16);
    const float w1 = __uint_as_float(pv.x & 0xFFFF0000u);
    const float w2 = __uint_as_float(pv.y << 16);
    const float w3 = __uint_as_float(pv.y & 0xFFFF0000u);
    const float w4 = __uint_as_float(pv.z << 16);
    const float w5 = __uint_as_float(pv.z & 0xFFFF0000u);
    const float w6 = __uint_as_float(pv.w << 16);
    const float w7 = __uint_as_float(pv.w & 0xFFFF0000u);
    #pragma unroll
    for (int r = 0; r < 8; ++r) {
        const float4 x0 = *reinterpret_cast<const float4*>(&buf[r][kbase]);
        const float4 x1 = *reinterpret_cast<const float4*>(&buf[r][kbase + 4]);
        acc[r] = fmaf(x0.x, w0, acc[r]);
        acc[r] = fmaf(x0.y, w1, acc[r]);
        acc[r] = fmaf(x0.z, w2, acc[r]);
        acc[r] = fmaf(x0.w, w3, acc[r]);
        acc[r] = fmaf(x1.x, w4, acc[r]);
        acc[r] = fmaf(x1.y, w5, acc[r]);
        acc[r] = fmaf(x1.z, w6, acc[r]);
        acc[r] = fmaf(x1.w, w7, acc[r]);
    }
}

__device__ __forceinline__ void ode_feval(
        float a0, float a1, float& o0, float& o1,
        int col, int kq, int lane, int wid, int swz,
        const char* smem, float (*bufA)[CDIM], float (*bufB)[CDIM],
        float (*pS)[16], float (*pQ)[16],
        const WRegs& w2,
        float bl1, float bl2, float gnv, float bnv) {
    const int r0 = kq * 2;
    bufA[r0][col]     = a0;
    bufA[r0 + 1][col] = a1;
    __syncthreads();

    // ---- GEMV1: W1 from LDS (swizzled b128), activations broadcast from bufA
    float acc[8];
    #pragma unroll
    for (int r = 0; r < 8; ++r) acc[r] = 0.0f;
    {
        const char* w1base = smem + (col << 9);
        #pragma unroll
        for (int c = 0; c < 8; ++c) {
            const int woff = ((c << 6) + (kq << 4)) ^ swz;
            const uint4 wv = *reinterpret_cast<const uint4*>(w1base + woff);
            fma_chunk(bufA, c * 32 + kq * 8, wv, acc);
        }
    }
    // kq-partial reduce in-wave (lanes 4c..4c+3 share a column)
    #pragma unroll
    for (int r = 0; r < 8; ++r) {
        acc[r] += __shfl_xor(acc[r], 1, 64);
        acc[r] += __shfl_xor(acc[r], 2, 64);
    }
    bufB[r0][col]     = fmaxf(acc[r0]     + bl1, 0.0f);
    bufB[r0 + 1][col] = fmaxf(acc[r0 + 1] + bl1, 0.0f);
    __syncthreads();

    // ---- GEMV2: W2 from registers
    #pragma unroll
    for (int r = 0; r < 8; ++r) acc[r] = 0.0f;
    fma_chunk(bufB, 0 * 32 + kq * 8, w2.m0, acc);
    fma_chunk(bufB, 1 * 32 + kq * 8, w2.m1, acc);
    fma_chunk(bufB, 2 * 32 + kq * 8, w2.m2, acc);
    fma_chunk(bufB, 3 * 32 + kq * 8, w2.m3, acc);
    fma_chunk(bufB, 4 * 32 + kq * 8, w2.m4, acc);
    fma_chunk(bufB, 5 * 32 + kq * 8, w2.m5, acc);
    fma_chunk(bufB, 6 * 32 + kq * 8, w2.m6, acc);
    fma_chunk(bufB, 7 * 32 + kq * 8, w2.m7, acc);
    #pragma unroll
    for (int r = 0; r < 8; ++r) {
        acc[r] += __shfl_xor(acc[r], 1, 64);
        acc[r] += __shfl_xor(acc[r], 2, 64);
    }
    const float v0 = acc[r0]     + bl2 + a0;
    const float v1 = acc[r0 + 1] + bl2 + a1;

    // ---- LayerNorm over 256 cols of rows r0, r0+1
    float s0 = v0, q0 = v0 * v0, s1 = v1, q1 = v1 * v1;
    #pragma unroll
    for (int off = 4; off <= 32; off <<= 1) {
        s0 += __shfl_xor(s0, off, 64);
        q0 += __shfl_xor(q0, off, 64);
        s1 += __shfl_xor(s1, off, 64);
        q1 += __shfl_xor(q1, off, 64);
    }
    if (lane < 4) {   // lane==kq here (col%16==0)
        pS[r0][wid] = s0; pQ[r0][wid] = q0;
        pS[r0 + 1][wid] = s1; pQ[r0 + 1][wid] = q1;
    }
    __syncthreads();
    float4 sA = *reinterpret_cast<const float4*>(&pS[r0][0]);
    float4 sB = *reinterpret_cast<const float4*>(&pS[r0][4]);
    float4 sC = *reinterpret_cast<const float4*>(&pS[r0][8]);
    float4 sD = *reinterpret_cast<const float4*>(&pS[r0][12]);
    float S0 = (sA.x+sA.y+sA.z+sA.w) + (sB.x+sB.y+sB.z+sB.w)
             + (sC.x+sC.y+sC.z+sC.w) + (sD.x+sD.y+sD.z+sD.w);
    sA = *reinterpret_cast<const float4*>(&pQ[r0][0]);
    sB = *reinterpret_cast<const float4*>(&pQ[r0][4]);
    sC = *reinterpret_cast<const float4*>(&pQ[r0][8]);
    sD = *reinterpret_cast<const float4*>(&pQ[r0][12]);
    float Q0 = (sA.x+sA.y+sA.z+sA.w) + (sB.x+sB.y+sB.z+sB.w)
             + (sC.x+sC.y+sC.z+sC.w) + (sD.x+sD.y+sD.z+sD.w);
    sA = *reinterpret_cast<const float4*>(&pS[r0+1][0]);
    sB = *reinterpret_cast<const float4*>(&pS[r0+1][4]);
    sC = *reinterpret_cast<const float4*>(&pS[r0+1][8]);
    sD = *reinterpret_cast<const float4*>(&pS[r0+1][12]);
    float S1 = (sA.x+sA.y+sA.z+sA.w) + (sB.x+sB.y+sB.z+sB.w)
             + (sC.x+sC.y+sC.z+sC.w) + (sD.x+sD.y+sD.z+sD.w);
    sA = *reinterpret_cast<const float4*>(&pQ[r0+1][0]);
    sB = *reinterpret_cast<const float4*>(&pQ[r0+1][4]);
    sC = *reinterpret_cast<const float4*>(&pQ[r0+1][8]);
    sD = *reinterpret_cast<const float4*>(&pQ[r0+1][12]);
    float Q1 = (sA.x+sA.y+sA.z+sA.w) + (sB.x+sB.y+sB.z+sB.w)
             + (sC.x+sC.y+sC.z+sC.w) + (sD.x+sD.y+sD.z+sD.w);
    const float m0 = S0 * (1.0f / CDIM);
    const float m1 = S1 * (1.0f / CDIM);
    const float rs0 = rsqrtf(Q0 * (1.0f / CDIM) - m0 * m0 + LN_EPS);
    const float rs1 = rsqrtf(Q1 * (1.0f / CDIM) - m1 * m1 + LN_EPS);
    o0 = (v0 - m0) * rs0 * gnv + bnv;
    o1 = (v1 - m1) * rs1 * gnv + bnv;
}

__global__ __launch_bounds__(1024) void ode_kernel(
        const float* __restrict__ X1,
        const float* __restrict__ WL1, const float* __restrict__ BL1,
        const float* __restrict__ WL2, const float* __restrict__ BL2,
        const float* __restrict__ GN, const float* __restrict__ BN,
        const float* __restrict__ G2, const float* __restrict__ B2,
        const int* __restrict__ LT, const int* __restrict__ NSTEP,
        float* __restrict__ OUT) {
    extern __shared__ char smem[];
    float (*bufA)[CDIM] = reinterpret_cast<float (*)[CDIM]>(smem + 131072);
    float (*bufB)[CDIM] = reinterpret_cast<float (*)[CDIM]>(smem + 139264);
    float (*pS)[16]     = reinterpret_cast<float (*)[16]>(smem + 147456);
    float (*pQ)[16]     = reinterpret_cast<float (*)[16]>(smem + 147968);

    const int t    = threadIdx.x;
    const int col  = t >> 2;
    const int kq   = t & 3;
    const int lane = t & 63;
    const int wid  = t >> 6;
    const int swz  = (col & 7) << 4;
    const int wg = blockIdx.x;
    const int b  = wg >> 5;
    const int rg = wg & 31;
    const int base = b * NTOK + rg * 8;
    int steps = LT[b];
    const int ns = NSTEP[0];
    if (steps > ns) steps = ns;

    // ---- stage W1 into LDS as swizzled bf16 (one-time)
    for (int i = 0; i < 64; ++i) {
        const int idx = i * 1024 + t;        // linear over [k][c], coalesced
        const int k = idx >> 8;
        const int c = idx & 255;
        const unsigned short hv = (unsigned short)bf16_rne(WL1[idx]);
        const int off = (c << 9) + (((k << 1)) ^ ((c & 7) << 4));
        *reinterpret_cast<unsigned short*>(smem + off) = hv;
    }
    // ---- W2 slice into registers (k = c*32 + kq*8 + j, column col)
    const float* p2 = WL2 + col;
    WRegs w2;
    w2.m0 = pack_w(p2, 0 * 32 + kq * 8);
    w2.m1 = pack_w(p2, 1 * 32 + kq * 8);
    w2.m2 = pack_w(p2, 2 * 32 + kq * 8);
    w2.m3 = pack_w(p2, 3 * 32 + kq * 8);
    w2.m4 = pack_w(p2, 4 * 32 + kq * 8);
    w2.m5 = pack_w(p2, 5 * 32 + kq * 8);
    w2.m6 = pack_w(p2, 6 * 32 + kq * 8);
    w2.m7 = pack_w(p2, 7 * 32 + kq * 8);
    __syncthreads();

    const float bl1 = BL1[col], bl2 = BL2[col];
    const float gnv = GN[col],  bnv = BN[col];
    const int r0 = kq * 2;

    float y0 = X1[(size_t)(base + r0) * CDIM + col];
    float y1 = X1[(size_t)(base + r0 + 1) * CDIM + col];

    for (int s = 0; s < steps; ++s) {
        float k10, k11, k20, k21, k30, k31, k40, k41, a0, a1;
        ode_feval(y0, y1, k10, k11, col, kq, lane, wid, swz, smem, bufA, bufB, pS, pQ, w2, bl1, bl2, gnv, bnv);
        a0 = fmaf(DT_STEP * (1.0f/3.0f), k10, y0);
        a1 = fmaf(DT_STEP * (1.0f/3.0f), k11, y1);
        ode_feval(a0, a1, k20, k21, col, kq, lane, wid, swz, smem, bufA, bufB, pS, pQ, w2, bl1, bl2, gnv, bnv);
        a0 = fmaf(DT_STEP, k20 - k10 * (1.0f/3.0f), y0);
        a1 = fmaf(DT_STEP, k21 - k11 * (1.0f/3.0f), y1);
        ode_feval(a0, a1, k30, k31, col, kq, lane, wid, swz, smem, bufA, bufB, pS, pQ, w2, bl1, bl2, gnv, bnv);
        a0 = fmaf(DT_STEP, k10 - k20 + k30, y0);
        a1 = fmaf(DT_STEP, k11 - k21 + k31, y1);
        ode_feval(a0, a1, k40, k41, col, kq, lane, wid, swz, smem, bufA, bufB, pS, pQ, w2, bl1, bl2, gnv, bnv);
        y0 = fmaf(DT_STEP * 0.125f, k10 + 3.0f * (k20 + k30) + k40, y0);
        y1 = fmaf(DT_STEP * 0.125f, k11 + 3.0f * (k21 + k31) + k41, y1);
    }

    // ---- final: OUT = LN(x1 + y, g2, b2) (same lane-mapped reduction)
    const float x10 = X1[(size_t)(base + r0) * CDIM + col];
    const float x11 = X1[(size_t)(base + r0 + 1) * CDIM + col];
    const float v0 = x10 + y0;
    const float v1 = x11 + y1;
    float s0 = v0, q0 = v0 * v0, s1 = v1, q1 = v1 * v1;
    #pragma unroll
    for (int off = 4; off <= 32; off <<= 1) {
        s0 += __shfl_xor(s0, off, 64);
        q0 += __shfl_xor(q0, off, 64);
        s1 += __shfl_xor(s1, off, 64);
        q1 += __shfl_xor(q1, off, 64);
    }
    __syncthreads();   // pS/pQ reuse: last feval's reads are done
    if (lane < 4) {
        pS[r0][wid] = s0; pQ[r0][wid] = q0;
        pS[r0 + 1][wid] = s1; pQ[r0 + 1][wid] = q1;
    }
    __syncthreads();
    float S0 = 0.0f, Q0 = 0.0f, S1 = 0.0f, Q1 = 0.0f;
    #pragma unroll
    for (int wv = 0; wv < 16; ++wv) {
        S0 += pS[r0][wv];     Q0 += pQ[r0][wv];
        S1 += pS[r0 + 1][wv]; Q1 += pQ[r0 + 1][wv];
    }
    const float m0 = S0 * (1.0f / CDIM);
    const float m1 = S1 * (1.0f / CDIM);
    const float rs0 = rsqrtf(Q0 * (1.0f / CDIM) - m0 * m0 + LN_EPS);
    const float rs1 = rsqrtf(Q1 * (1.0f / CDIM) - m1 * m1 + LN_EPS);
    const float g2 = G2[col], b2 = B2[col];
    OUT[(size_t)(base + r0) * CDIM + col]     = (v0 - m0) * rs0 * g2 + b2;
    OUT[(size_t)(base + r0 + 1) * CDIM + col] = (v1 - m1) * rs1 * g2 + b2;
}

// ---------------------------------------------------------------------------
extern "C" void kernel_launch(void* const* d_in, const int* in_sizes, int n_in,
                              void* d_out, int out_size, void* d_ws, size_t ws_size,
                              hipStream_t stream) {
    const float* x    = (const float*)d_in[0];
    const float* wqkv = (const float*)d_in[1];
    const float* bqkv = (const float*)d_in[2];
    const float* wo   = (const float*)d_in[3];
    const float* bo   = (const float*)d_in[4];
    const float* g1   = (const float*)d_in[5];
    const float* b1   = (const float*)d_in[6];
    const float* g2   = (const float*)d_in[7];
    const float* b2   = (const float*)d_in[8];
    const float* wl1  = (const float*)d_in[9];
    const float* bl1  = (const float*)d_in[10];
    const float* wl2  = (const float*)d_in[11];
    const float* bl2  = (const float*)d_in[12];
    const float* gn   = (const float*)d_in[13];
    const float* bn   = (const float*)d_in[14];
    const int*   lt   = (const int*)d_in[15];
    const int*   nst  = (const int*)d_in[16];

    float* ws  = (float*)d_ws;
    float* qkv = ws;                              // M*768
    float* po  = qkv + (size_t)MROWS * 768;       // M*256
    float* x1  = po  + (size_t)MROWS * CDIM;      // M*256
    float* out = (float*)d_out;

    // Opt in to >64 KiB dynamic LDS (host-side, graph-capture safe, idempotent).
    (void)hipFuncSetAttribute(reinterpret_cast<const void*>(ode_kernel),
                              hipFuncAttributeMaxDynamicSharedMemorySize,
                              ODE_LDS_BYTES);

    hipLaunchKernelGGL(qkv_kernel, dim3(MROWS / 8), dim3(256), 0, stream,
                       x, wqkv, bqkv, qkv);
    hipLaunchKernelGGL(attn_kernel, dim3(BSZ * NHEAD), dim3(256), 0, stream,
                       qkv, po);
    hipLaunchKernelGGL(oproj_ln_kernel, dim3(MROWS / 8), dim3(256), 0, stream,
                       po, wo, bo, x, g1, b1, x1);
    hipLaunchKernelGGL(ode_kernel, dim3(MROWS / 8), dim3(1024), ODE_LDS_BYTES, stream,
                       x1, wl1, bl1, wl2, bl2, gn, bn, g2, b2, lt, nst, out);
}